// Round 7
// baseline (18218.376 us; speedup 1.0000x reference)
//
#include <hip/hip_runtime.h>
#include <math.h>

// Problem dims (fixed by setup_inputs)
#define B_ROWS 65536
#define DDIM   512
#define NG     4
#define NK     1024
#define NH     128
#define NA     7

// Tiling: 8 waves = 4 row-groups (TR=8 rows) x 2 cw-groups (TC=8 consecutive
// codewords per lane). LDS b128-reads per step = TR+TC = 16 per 256 FMAs.
#define BM       32            // rows per block
#define NTHREADS 512           // 8 waves
#define TR       8             // rows per lane
#define TC       8             // consecutive codewords per lane
#define CWCHUNK  1024          // codeword tile width = whole codebook
#define KCHUNK   8             // k tile (double-buffered)
#define NKC      (DDIM / KCHUNK)     // 64
#define KC_SPLIT 48            // kc<48 -> accA (k<384, OpenBLAS GEMM_Q block)

// LDS layout
#define BT_ELEMS  (KCHUNK * CWCHUNK)                 // 8192 floats per buffer
#define OFF_BTILE (BM * DDIM * 4)                    // 65536
#define OFF_H1    (OFF_BTILE + 2 * BT_ELEMS * 4)     // 131072
#define OFF_REDS  (OFF_H1 + BM * NH * 4)             // 147456
#define OFF_REDI  (OFF_REDS + 2 * BM * 4)            // 147712
#define OFF_IDX   (OFF_REDI + 2 * BM * 4)            // 147968
#define LDS_BYTES (OFF_IDX + NG * BM * 4)            // 148480

// ---------------------------------------------------------------------------
// 0.5 * ||c||^2 emulating numpy fp32 np.sum(C*C, axis=-1):
// pairwise_sum, AVX512 SIMD variant (vstep=16, PW_BLOCKSIZE=128).
// fp contract OFF: each square rounds before add (C*C is a materialized array).
// ---------------------------------------------------------------------------
__global__ void rvq_norms_np(const float* __restrict__ cb,
                             float* __restrict__ halfnorm) {
#pragma clang fp contract(off)
    int k = blockIdx.x * blockDim.x + threadIdx.x;
    if (k >= NG * NK) return;
    const float* c = cb + (size_t)k * DDIM;
    float blk[4];
#pragma unroll
    for (int b = 0; b < 4; ++b) {
        const float* p = c + b * 128;
        float s[16];
#pragma unroll
        for (int l = 0; l < 16; ++l) {
            float x0 = p[l],      x1 = p[l + 16], x2 = p[l + 32], x3 = p[l + 48];
            float x4 = p[l + 64], x5 = p[l + 80], x6 = p[l + 96], x7 = p[l + 112];
            float pa = x0 * x0 + x4 * x4;
            float pb = x1 * x1 + x5 * x5;
            float pc = x2 * x2 + x6 * x6;
            float pd = x3 * x3 + x7 * x7;
            s[l] = (pa + pb) + (pc + pd);
        }
        float h[8];
#pragma unroll
        for (int l = 0; l < 8; ++l) h[l] = s[l] + s[l + 8];
        float q[4];
#pragma unroll
        for (int l = 0; l < 4; ++l) q[l] = h[l] + h[l + 4];
        float r0 = q[0] + q[2];
        float r1 = q[1] + q[3];
        blk[b] = r0 + r1;
    }
    float total = (blk[0] + blk[1]) + (blk[2] + blk[3]);
    halfnorm[k] = 0.5f * total;
}

// One k-chunk of the bit-exact sequential fp32 FMA chain (ascending d).
// B: 2 x b128 of consecutive cw per dd (conflict-free). A: wave-uniform b128.
#define COMPUTE_CHUNK(BT, ACC)                                                \
    _Pragma("unroll")                                                         \
    for (int d4 = 0; d4 < KCHUNK; d4 += 4) {                                  \
        float bqf[4][TC];                                                     \
        _Pragma("unroll")                                                     \
        for (int dd = 0; dd < 4; ++dd) {                                      \
            float4 t0 = *(const float4*)&BT[(d4 + dd) * CWCHUNK + bcol0];     \
            float4 t1 = *(const float4*)&BT[(d4 + dd) * CWCHUNK + bcol0 + 4]; \
            bqf[dd][0] = t0.x; bqf[dd][1] = t0.y;                             \
            bqf[dd][2] = t0.z; bqf[dd][3] = t0.w;                             \
            bqf[dd][4] = t1.x; bqf[dd][5] = t1.y;                             \
            bqf[dd][6] = t1.z; bqf[dd][7] = t1.w;                             \
        }                                                                     \
        _Pragma("unroll")                                                     \
        for (int r = 0; r < TR; ++r) {                                        \
            float4 av = *(const float4*)&resid[(r0 + r) * DDIM + kb + d4];    \
            _Pragma("unroll")                                                 \
            for (int j = 0; j < TC; ++j) {                                    \
                ACC[r][j] = fmaf(av.x, bqf[0][j], ACC[r][j]);                 \
                ACC[r][j] = fmaf(av.y, bqf[1][j], ACC[r][j]);                 \
                ACC[r][j] = fmaf(av.z, bqf[2][j], ACC[r][j]);                 \
                ACC[r][j] = fmaf(av.w, bqf[3][j], ACC[r][j]);                 \
            }                                                                 \
        }                                                                     \
    }

// ---------------------------------------------------------------------------
// Fused: residual VQ (4 stages, np-fp32-emulated scoring, LDS-tiled GEMM with
// double-buffered B tile) + reference-order quantized sum + straight-through
// + MLP (512->128->128->7).
// ---------------------------------------------------------------------------
__global__ __launch_bounds__(NTHREADS, 2) void rvq_mlp_fused(
    const float* __restrict__ z, const float* __restrict__ cb,
    const float* __restrict__ halfnorm,
    const float* __restrict__ w1, const float* __restrict__ b1,
    const float* __restrict__ w2, const float* __restrict__ b2,
    const float* __restrict__ w3, const float* __restrict__ b3,
    float* __restrict__ out) {
    extern __shared__ char smem[];
    float* resid = (float*)smem;                   // [BM][DDIM]
    float* Bt    = (float*)(smem + OFF_BTILE);     // [2][KCHUNK][CWCHUNK]
    float* h1    = (float*)(smem + OFF_H1);        // [BM][NH]
    float* redS  = (float*)(smem + OFF_REDS);      // [2][BM]
    int*   redI  = (int*)(smem + OFF_REDI);        // [2][BM]
    int*   idx_s = (int*)(smem + OFF_IDX);         // [NG][BM]

    const int tid = threadIdx.x;
    const size_t row0 = (size_t)blockIdx.x * BM;

    // ---- 1) load z tile into LDS ----
    {
        const float4* src = (const float4*)(z + row0 * DDIM);
        float4* dst = (float4*)resid;
#pragma unroll
        for (int i = 0; i < (BM * DDIM / 4) / NTHREADS; ++i)
            dst[tid + i * NTHREADS] = src[tid + i * NTHREADS];
    }
    __syncthreads();

    const int cg    = tid & 63;       // lane
    const int wv    = tid >> 6;       // wave 0..7
    const int rgrp  = wv & 3;         // row-group (8 rows each)
    const int cwgrp = wv >> 2;        // cw-group (512 cw each)
    const int r0    = rgrp * TR;
    const int bcol0 = cwgrp * 512 + cg * TC;   // lane cols: bcol0 + j

    // staging identity: thread stages cw pair (2*tid, 2*tid+1), 8 k each
    const int scw0 = 2 * tid;

    // ---- 2) residual VQ stages ----
    for (int g = 0; g < NG; ++g) {
        const float* C  = cb + (size_t)g * NK * DDIM;
        const float* hn = halfnorm + g * NK;

        const float* s0 = C + (size_t)scw0 * DDIM;
        const float* s1 = s0 + DDIM;

        float sb[TR]; int ib[TR];
#pragma unroll
        for (int r = 0; r < TR; ++r) { sb[r] = -3.4e38f; ib[r] = 0; }

        float accA[TR][TC], accB[TR][TC];
#pragma unroll
        for (int r = 0; r < TR; ++r)
#pragma unroll
            for (int j = 0; j < TC; ++j) { accA[r][j] = 0.f; accB[r][j] = 0.f; }

        // prologue: stage k-chunk 0 -> buf0 (b64 writes of cw pairs)
        {
            float4 a0 = *(const float4*)(s0);
            float4 a1 = *(const float4*)(s0 + 4);
            float4 b0 = *(const float4*)(s1);
            float4 b1 = *(const float4*)(s1 + 4);
            const float* a0f = (const float*)&a0;
            const float* a1f = (const float*)&a1;
            const float* b0f = (const float*)&b0;
            const float* b1f = (const float*)&b1;
#pragma unroll
            for (int k = 0; k < 4; ++k) {
                *(float2*)&Bt[k * CWCHUNK + scw0] = make_float2(a0f[k], b0f[k]);
                *(float2*)&Bt[(4 + k) * CWCHUNK + scw0] = make_float2(a1f[k], b1f[k]);
            }
        }

        for (int kc = 0; kc < NKC; ++kc) {
            const int kb = kc * KCHUNK;
            __syncthreads();   // buf[kc&1] visible; readers of buf[(kc+1)&1] done
            float4 a0, a1, b0, b1;
            if (kc + 1 < NKC) {   // T14: issue next-chunk loads early
                a0 = *(const float4*)(s0 + kb + KCHUNK);
                a1 = *(const float4*)(s0 + kb + KCHUNK + 4);
                b0 = *(const float4*)(s1 + kb + KCHUNK);
                b1 = *(const float4*)(s1 + kb + KCHUNK + 4);
            }
            const float* bt = Bt + (kc & 1) * BT_ELEMS;
            if (kc < KC_SPLIT) { COMPUTE_CHUNK(bt, accA) }
            else               { COMPUTE_CHUNK(bt, accB) }
            if (kc + 1 < NKC) {   // write-late into the idle buffer
                float* btN = Bt + ((kc + 1) & 1) * BT_ELEMS;
                const float* a0f = (const float*)&a0;
                const float* a1f = (const float*)&a1;
                const float* b0f = (const float*)&b0;
                const float* b1f = (const float*)&b1;
#pragma unroll
                for (int k = 0; k < 4; ++k) {
                    *(float2*)&btN[k * CWCHUNK + scw0] = make_float2(a0f[k], b0f[k]);
                    *(float2*)&btN[(4 + k) * CWCHUNK + scw0] = make_float2(a1f[k], b1f[k]);
                }
            }
        }

        // score = fl(S1+S2) - hn ; running argmax (j ascending -> candidates
        // ascending per lane -> strict > keeps first occurrence)
#pragma unroll
        for (int j = 0; j < TC; ++j) {
            const int cod = bcol0 + j;
            const float hnv = hn[cod];
#pragma unroll
            for (int r = 0; r < TR; ++r) {
                float s = (accA[r][j] + accB[r][j]) - hnv;
                if (s > sb[r]) { sb[r] = s; ib[r] = cod; }
            }
        }

        // ---- butterfly argmax within wave (ties -> lower index) ----
#pragma unroll
        for (int m = 32; m >= 1; m >>= 1) {
#pragma unroll
            for (int r = 0; r < TR; ++r) {
                float os = __shfl_xor(sb[r], m, 64);
                int   oi = __shfl_xor(ib[r], m, 64);
                if (os > sb[r] || (os == sb[r] && oi < ib[r])) {
                    sb[r] = os; ib[r] = oi;
                }
            }
        }
        if (cg == 0) {
#pragma unroll
            for (int r = 0; r < TR; ++r) {
                redS[cwgrp * BM + r0 + r] = sb[r];
                redI[cwgrp * BM + r0 + r] = ib[r];
            }
        }
        __syncthreads();
        // combine the two cw-groups per row (global first-occurrence ties)
        if (tid < BM) {
            float sA = redS[tid], sB = redS[BM + tid];
            int   iA = redI[tid], iB = redI[BM + tid];
            idx_s[g * BM + tid] =
                (sB > sA || (sB == sA && iB < iA)) ? iB : iA;
        }
        __syncthreads();

        // ---- residual -= chosen codeword (exact fp32); skip after last ----
        if (g < NG - 1) {
            const int row = tid >> 4;
            const int sub = tid & 15;
            const float4* crow =
                (const float4*)(C + (size_t)idx_s[g * BM + row] * DDIM);
            float4* rrow = (float4*)&resid[row * DDIM];
#pragma unroll
            for (int k = 0; k < 8; ++k) {
                int p = sub + k * 16;
                float4 rv = rrow[p], cv = crow[p];
                rv.x -= cv.x; rv.y -= cv.y; rv.z -= cv.z; rv.w -= cv.w;
                rrow[p] = rv;
            }
            __syncthreads();
        }
    }

    // ---- 3) st = z + (zq - z), zq in reference order (((0+q0)+q1)+q2)+q3 ----
    {
        const int row = tid >> 4;
        const int sub = tid & 15;
        const float4* zrow = (const float4*)(z + (row0 + row) * DDIM);
        float4* rrow = (float4*)&resid[row * DDIM];
        const float4* c0 = (const float4*)(cb + ((size_t)0 * NK + idx_s[0 * BM + row]) * DDIM);
        const float4* c1 = (const float4*)(cb + ((size_t)1 * NK + idx_s[1 * BM + row]) * DDIM);
        const float4* c2 = (const float4*)(cb + ((size_t)2 * NK + idx_s[2 * BM + row]) * DDIM);
        const float4* c3 = (const float4*)(cb + ((size_t)3 * NK + idx_s[3 * BM + row]) * DDIM);
#pragma unroll
        for (int k = 0; k < 8; ++k) {
            int p = sub + k * 16;
            float4 q0 = c0[p], q1 = c1[p], q2 = c2[p], q3 = c3[p];
            float4 q;
            q.x = ((q0.x + q1.x) + q2.x) + q3.x;
            q.y = ((q0.y + q1.y) + q2.y) + q3.y;
            q.z = ((q0.z + q1.z) + q2.z) + q3.z;
            q.w = ((q0.w + q1.w) + q2.w) + q3.w;
            float4 zv = zrow[p];
            float4 st;
            st.x = zv.x + (q.x - zv.x);
            st.y = zv.y + (q.y - zv.y);
            st.z = zv.z + (q.z - zv.z);
            st.w = zv.w + (q.w - zv.w);
            rrow[p] = st;
        }
    }
    __syncthreads();

    const int colg = tid & 31;
    const int rowg = tid >> 5;
    const int c0_  = colg * 4;
    const int hr0  = rowg * 2;

    // ---- 4) h1 = relu(st @ w1 + b1) ----
    {
        float acc[2][4] = {{0.f, 0.f, 0.f, 0.f}, {0.f, 0.f, 0.f, 0.f}};
        for (int d = 0; d < DDIM; d += 4) {
            float4 a0 = *(const float4*)&resid[hr0 * DDIM + d];
            float4 a1 = *(const float4*)&resid[(hr0 + 1) * DDIM + d];
            float a0f[4] = {a0.x, a0.y, a0.z, a0.w};
            float a1f[4] = {a1.x, a1.y, a1.z, a1.w};
#pragma unroll
            for (int dd = 0; dd < 4; ++dd) {
                float4 wv2 = *(const float4*)&w1[(size_t)(d + dd) * NH + c0_];
                acc[0][0] = fmaf(a0f[dd], wv2.x, acc[0][0]);
                acc[0][1] = fmaf(a0f[dd], wv2.y, acc[0][1]);
                acc[0][2] = fmaf(a0f[dd], wv2.z, acc[0][2]);
                acc[0][3] = fmaf(a0f[dd], wv2.w, acc[0][3]);
                acc[1][0] = fmaf(a1f[dd], wv2.x, acc[1][0]);
                acc[1][1] = fmaf(a1f[dd], wv2.y, acc[1][1]);
                acc[1][2] = fmaf(a1f[dd], wv2.z, acc[1][2]);
                acc[1][3] = fmaf(a1f[dd], wv2.w, acc[1][3]);
            }
        }
        float4 bv = *(const float4*)&b1[c0_];
        float bf[4] = {bv.x, bv.y, bv.z, bv.w};
#pragma unroll
        for (int r = 0; r < 2; ++r) {
            float4 o;
            o.x = fmaxf(acc[r][0] + bf[0], 0.f);
            o.y = fmaxf(acc[r][1] + bf[1], 0.f);
            o.z = fmaxf(acc[r][2] + bf[2], 0.f);
            o.w = fmaxf(acc[r][3] + bf[3], 0.f);
            *(float4*)&h1[(hr0 + r) * NH + c0_] = o;
        }
    }
    __syncthreads();

    // ---- 5) h2 = relu(h1 @ w2 + b2), stored into resid region ----
    float* h2 = resid;
    {
        float acc[2][4] = {{0.f, 0.f, 0.f, 0.f}, {0.f, 0.f, 0.f, 0.f}};
        for (int d = 0; d < NH; d += 4) {
            float4 a0 = *(const float4*)&h1[hr0 * NH + d];
            float4 a1 = *(const float4*)&h1[(hr0 + 1) * NH + d];
            float a0f[4] = {a0.x, a0.y, a0.z, a0.w};
            float a1f[4] = {a1.x, a1.y, a1.z, a1.w};
#pragma unroll
            for (int dd = 0; dd < 4; ++dd) {
                float4 wv2 = *(const float4*)&w2[(size_t)(d + dd) * NH + c0_];
                acc[0][0] = fmaf(a0f[dd], wv2.x, acc[0][0]);
                acc[0][1] = fmaf(a0f[dd], wv2.y, acc[0][1]);
                acc[0][2] = fmaf(a0f[dd], wv2.z, acc[0][2]);
                acc[0][3] = fmaf(a0f[dd], wv2.w, acc[0][3]);
                acc[1][0] = fmaf(a1f[dd], wv2.x, acc[1][0]);
                acc[1][1] = fmaf(a1f[dd], wv2.y, acc[1][1]);
                acc[1][2] = fmaf(a1f[dd], wv2.z, acc[1][2]);
                acc[1][3] = fmaf(a1f[dd], wv2.w, acc[1][3]);
            }
        }
        float4 bv = *(const float4*)&b2[c0_];
        float bf[4] = {bv.x, bv.y, bv.z, bv.w};
        __syncthreads();
#pragma unroll
        for (int r = 0; r < 2; ++r) {
            float4 o;
            o.x = fmaxf(acc[r][0] + bf[0], 0.f);
            o.y = fmaxf(acc[r][1] + bf[1], 0.f);
            o.z = fmaxf(acc[r][2] + bf[2], 0.f);
            o.w = fmaxf(acc[r][3] + bf[3], 0.f);
            *(float4*)&h2[(hr0 + r) * NH + c0_] = o;
        }
    }
    __syncthreads();

    // ---- 6) out = h2 @ w3 + b3 ----
    if (tid < BM * NA) {
        const int r = tid / NA;
        const int a = tid - r * NA;
        const float* h2r = &h2[r * NH];
        float s = b3[a];
        for (int h = 0; h < NH; ++h)
            s = fmaf(h2r[h], w3[(size_t)h * NA + a], s);
        out[(row0 + r) * NA + a] = s;
    }
}

extern "C" void kernel_launch(void* const* d_in, const int* in_sizes, int n_in,
                              void* d_out, int out_size, void* d_ws, size_t ws_size,
                              hipStream_t stream) {
    const float* z  = (const float*)d_in[0];
    const float* cb = (const float*)d_in[1];
    const float* w1 = (const float*)d_in[2];
    const float* b1 = (const float*)d_in[3];
    const float* w2 = (const float*)d_in[4];
    const float* b2 = (const float*)d_in[5];
    const float* w3 = (const float*)d_in[6];
    const float* b3 = (const float*)d_in[7];
    float* out = (float*)d_out;
    float* halfnorm = (float*)d_ws;   // NG*NK floats = 16 KB

    (void)hipFuncSetAttribute((const void*)rvq_mlp_fused,
                              hipFuncAttributeMaxDynamicSharedMemorySize,
                              LDS_BYTES);

    rvq_norms_np<<<dim3((NG * NK + 255) / 256), dim3(256), 0, stream>>>(cb, halfnorm);
    rvq_mlp_fused<<<dim3(B_ROWS / BM), dim3(NTHREADS), LDS_BYTES, stream>>>(
        z, cb, halfnorm, w1, b1, w2, b2, w3, b3, out);
}

// Round 8
// 9349.322 us; speedup vs baseline: 1.9486x; 1.9486x over previous
//
#include <hip/hip_runtime.h>
#include <math.h>

// Problem dims (fixed by setup_inputs)
#define B_ROWS 65536
#define DDIM   512
#define NG     4
#define NK     1024
#define NH     128
#define NA     7

// Tiling: 8 waves = 4 row-groups (TR=8 rows) x 2 cw-groups.
// Lane covers TC=8 codewords as TWO 4-consecutive groups (cg*4, cg*4+256)
// -> every B ds_read_b128 has the wave covering 256 contiguous dwords
//    (conflict-free; r7's cg*8 stride-32B pattern was a 16-way conflict).
#define BM       32            // rows per block
#define NTHREADS 512           // 8 waves
#define TR       8             // rows per lane
#define TC       8             // codewords per lane (2 groups of 4)
#define CWCHUNK  1024          // whole codebook per pass (single pass)
#define KCHUNK   8             // k tile (double-buffered)
#define NKC      (DDIM / KCHUNK)     // 64
#define KC_SPLIT 48            // kc<48 -> accA (k<384, OpenBLAS GEMM_Q block)

// LDS layout
#define BT_ELEMS  (KCHUNK * CWCHUNK)                 // 8192 floats per buffer
#define OFF_BTILE (BM * DDIM * 4)                    // 65536
#define OFF_H1    (OFF_BTILE + 2 * BT_ELEMS * 4)     // 131072
#define OFF_REDS  (OFF_H1 + BM * NH * 4)             // 147456
#define OFF_REDI  (OFF_REDS + 2 * BM * 4)            // 147712
#define OFF_IDX   (OFF_REDI + 2 * BM * 4)            // 147968
#define LDS_BYTES (OFF_IDX + NG * BM * 4)            // 148480

// ---------------------------------------------------------------------------
// 0.5 * ||c||^2 emulating numpy fp32 np.sum(C*C, axis=-1):
// pairwise_sum, AVX512 SIMD variant (vstep=16, PW_BLOCKSIZE=128).
// fp contract OFF: each square rounds before add.
// ---------------------------------------------------------------------------
__global__ void rvq_norms_np(const float* __restrict__ cb,
                             float* __restrict__ halfnorm) {
#pragma clang fp contract(off)
    int k = blockIdx.x * blockDim.x + threadIdx.x;
    if (k >= NG * NK) return;
    const float* c = cb + (size_t)k * DDIM;
    float blk[4];
#pragma unroll
    for (int b = 0; b < 4; ++b) {
        const float* p = c + b * 128;
        float s[16];
#pragma unroll
        for (int l = 0; l < 16; ++l) {
            float x0 = p[l],      x1 = p[l + 16], x2 = p[l + 32], x3 = p[l + 48];
            float x4 = p[l + 64], x5 = p[l + 80], x6 = p[l + 96], x7 = p[l + 112];
            float pa = x0 * x0 + x4 * x4;
            float pb = x1 * x1 + x5 * x5;
            float pc = x2 * x2 + x6 * x6;
            float pd = x3 * x3 + x7 * x7;
            s[l] = (pa + pb) + (pc + pd);
        }
        float h[8];
#pragma unroll
        for (int l = 0; l < 8; ++l) h[l] = s[l] + s[l + 8];
        float q[4];
#pragma unroll
        for (int l = 0; l < 4; ++l) q[l] = h[l] + h[l + 4];
        float r0 = q[0] + q[2];
        float r1 = q[1] + q[3];
        blk[b] = r0 + r1;
    }
    float total = (blk[0] + blk[1]) + (blk[2] + blk[3]);
    halfnorm[k] = 0.5f * total;
}

// One k-chunk (8 k) of the bit-exact sequential fp32 FMA chain (ascending k:
// d4 asc, dd asc). A: TR uniform b128 per step. B: 2 contiguous b128 per dd.
#define COMPUTE_CHUNK(BT, ACC)                                                \
    _Pragma("unroll")                                                         \
    for (int d4 = 0; d4 < KCHUNK; d4 += 4) {                                  \
        float avf[TR][4];                                                     \
        _Pragma("unroll")                                                     \
        for (int r = 0; r < TR; ++r) {                                        \
            float4 av = *(const float4*)&resid[(r0 + r) * DDIM + kb + d4];    \
            avf[r][0] = av.x; avf[r][1] = av.y;                               \
            avf[r][2] = av.z; avf[r][3] = av.w;                               \
        }                                                                     \
        _Pragma("unroll")                                                     \
        for (int dd = 0; dd < 4; ++dd) {                                      \
            float4 b0 = *(const float4*)&BT[(d4 + dd) * CWCHUNK + bcol0];     \
            float4 b1 = *(const float4*)&BT[(d4 + dd) * CWCHUNK + bcol0 + 256];\
            _Pragma("unroll")                                                 \
            for (int r = 0; r < TR; ++r) {                                    \
                const float a = avf[r][dd];                                   \
                ACC[r][0] = fmaf(a, b0.x, ACC[r][0]);                         \
                ACC[r][1] = fmaf(a, b0.y, ACC[r][1]);                         \
                ACC[r][2] = fmaf(a, b0.z, ACC[r][2]);                         \
                ACC[r][3] = fmaf(a, b0.w, ACC[r][3]);                         \
                ACC[r][4] = fmaf(a, b1.x, ACC[r][4]);                         \
                ACC[r][5] = fmaf(a, b1.y, ACC[r][5]);                         \
                ACC[r][6] = fmaf(a, b1.z, ACC[r][6]);                         \
                ACC[r][7] = fmaf(a, b1.w, ACC[r][7]);                         \
            }                                                                 \
        }                                                                     \
    }

// ---------------------------------------------------------------------------
// Fused: residual VQ (4 stages, np-fp32-emulated scoring, LDS-tiled GEMM with
// double-buffered transposed B tile) + reference-order quantized sum +
// straight-through + MLP (512->128->128->7).
// ---------------------------------------------------------------------------
__attribute__((amdgpu_waves_per_eu(2, 2)))
__global__ __launch_bounds__(NTHREADS) void rvq_mlp_fused(
    const float* __restrict__ z, const float* __restrict__ cb,
    const float* __restrict__ halfnorm,
    const float* __restrict__ w1, const float* __restrict__ b1,
    const float* __restrict__ w2, const float* __restrict__ b2,
    const float* __restrict__ w3, const float* __restrict__ b3,
    float* __restrict__ out) {
    extern __shared__ char smem[];
    float* resid = (float*)smem;                   // [BM][DDIM]
    float* Bt    = (float*)(smem + OFF_BTILE);     // [2][KCHUNK][CWCHUNK]
    float* h1    = (float*)(smem + OFF_H1);        // [BM][NH]
    float* redS  = (float*)(smem + OFF_REDS);      // [2][BM]
    int*   redI  = (int*)(smem + OFF_REDI);        // [2][BM]
    int*   idx_s = (int*)(smem + OFF_IDX);         // [NG][BM]

    const int tid = threadIdx.x;
    const size_t row0 = (size_t)blockIdx.x * BM;

    // ---- 1) load z tile into LDS ----
    {
        const float4* src = (const float4*)(z + row0 * DDIM);
        float4* dst = (float4*)resid;
#pragma unroll
        for (int i = 0; i < (BM * DDIM / 4) / NTHREADS; ++i)
            dst[tid + i * NTHREADS] = src[tid + i * NTHREADS];
    }
    __syncthreads();

    const int cg    = tid & 63;       // lane
    const int wv    = tid >> 6;       // wave 0..7
    const int rgrp  = wv & 3;         // row-group (8 rows each)
    const int cwgrp = wv >> 2;        // cw-group (512 cw each)
    const int r0    = rgrp * TR;
    const int bcol0 = cwgrp * 512 + cg * 4;   // lane cols: bcol0+{0..3}, +256+{0..3}

    // staging identity: thread stages a 4cw x 4k tile
    const int scw4 = (tid >> 1) * 4;      // 0,4,...,1020
    const int sk4  = (tid & 1) * 4;       // 0 or 4

    // ---- 2) residual VQ stages ----
    for (int g = 0; g < NG; ++g) {
        const float* C  = cb + (size_t)g * NK * DDIM;
        const float* hn = halfnorm + g * NK;
        const float* sbase = C + (size_t)scw4 * DDIM + sk4;

        float sb[TR]; int ib[TR];
#pragma unroll
        for (int r = 0; r < TR; ++r) { sb[r] = -3.4e38f; ib[r] = 0; }

        float accA[TR][TC], accB[TR][TC];
#pragma unroll
        for (int r = 0; r < TR; ++r)
#pragma unroll
            for (int j = 0; j < TC; ++j) { accA[r][j] = 0.f; accB[r][j] = 0.f; }

        // prologue: stage k-chunk 0 -> buf0 (transposed b128 writes)
        {
            float mf[4][4];
#pragma unroll
            for (int i = 0; i < 4; ++i) {
                float4 m = *(const float4*)(sbase + (size_t)i * DDIM);
                mf[i][0] = m.x; mf[i][1] = m.y; mf[i][2] = m.z; mf[i][3] = m.w;
            }
#pragma unroll
            for (int dd = 0; dd < 4; ++dd)
                *(float4*)&Bt[(sk4 + dd) * CWCHUNK + scw4] =
                    make_float4(mf[0][dd], mf[1][dd], mf[2][dd], mf[3][dd]);
        }

        for (int kc = 0; kc < NKC; ++kc) {
            const int kb = kc * KCHUNK;
            __syncthreads();   // buf[kc&1] visible; readers of buf[(kc+1)&1] done
            float mf[4][4];
            if (kc + 1 < NKC) {   // T14: issue next-chunk loads early
#pragma unroll
                for (int i = 0; i < 4; ++i) {
                    float4 m = *(const float4*)(sbase + (size_t)i * DDIM + kb + KCHUNK);
                    mf[i][0] = m.x; mf[i][1] = m.y; mf[i][2] = m.z; mf[i][3] = m.w;
                }
            }
            const float* bt = Bt + (kc & 1) * BT_ELEMS;
            if (kc < KC_SPLIT) { COMPUTE_CHUNK(bt, accA) }
            else               { COMPUTE_CHUNK(bt, accB) }
            if (kc + 1 < NKC) {   // write-late into the idle buffer
                float* btN = Bt + ((kc + 1) & 1) * BT_ELEMS;
#pragma unroll
                for (int dd = 0; dd < 4; ++dd)
                    *(float4*)&btN[(sk4 + dd) * CWCHUNK + scw4] =
                        make_float4(mf[0][dd], mf[1][dd], mf[2][dd], mf[3][dd]);
            }
        }

        // score = fl(S1+S2) - hn ; candidates ascending per lane
        // (j 0..3 -> bcol0+j ; j 4..7 -> bcol0+256+(j-4)) -> strict > keeps
        // first occurrence
#pragma unroll
        for (int j = 0; j < TC; ++j) {
            const int cod = bcol0 + (j < 4 ? j : 256 + (j - 4));
            const float hnv = hn[cod];
#pragma unroll
            for (int r = 0; r < TR; ++r) {
                float s = (accA[r][j] + accB[r][j]) - hnv;
                if (s > sb[r]) { sb[r] = s; ib[r] = cod; }
            }
        }

        // ---- butterfly argmax within wave (ties -> lower index) ----
#pragma unroll
        for (int m = 32; m >= 1; m >>= 1) {
#pragma unroll
            for (int r = 0; r < TR; ++r) {
                float os = __shfl_xor(sb[r], m, 64);
                int   oi = __shfl_xor(ib[r], m, 64);
                if (os > sb[r] || (os == sb[r] && oi < ib[r])) {
                    sb[r] = os; ib[r] = oi;
                }
            }
        }
        if (cg == 0) {
#pragma unroll
            for (int r = 0; r < TR; ++r) {
                redS[cwgrp * BM + r0 + r] = sb[r];
                redI[cwgrp * BM + r0 + r] = ib[r];
            }
        }
        __syncthreads();
        // combine the two cw-groups per row (global first-occurrence ties)
        if (tid < BM) {
            float sA = redS[tid], sB = redS[BM + tid];
            int   iA = redI[tid], iB = redI[BM + tid];
            idx_s[g * BM + tid] =
                (sB > sA || (sB == sA && iB < iA)) ? iB : iA;
        }
        __syncthreads();

        // ---- residual -= chosen codeword (exact fp32); skip after last ----
        if (g < NG - 1) {
            const int row = tid >> 4;
            const int sub = tid & 15;
            const float4* crow =
                (const float4*)(C + (size_t)idx_s[g * BM + row] * DDIM);
            float4* rrow = (float4*)&resid[row * DDIM];
#pragma unroll
            for (int k = 0; k < 8; ++k) {
                int p = sub + k * 16;
                float4 rv = rrow[p], cv = crow[p];
                rv.x -= cv.x; rv.y -= cv.y; rv.z -= cv.z; rv.w -= cv.w;
                rrow[p] = rv;
            }
            __syncthreads();
        }
    }

    // ---- 3) st = z + (zq - z), zq in reference order (((0+q0)+q1)+q2)+q3 ----
    {
        const int row = tid >> 4;
        const int sub = tid & 15;
        const float4* zrow = (const float4*)(z + (row0 + row) * DDIM);
        float4* rrow = (float4*)&resid[row * DDIM];
        const float4* c0 = (const float4*)(cb + ((size_t)0 * NK + idx_s[0 * BM + row]) * DDIM);
        const float4* c1 = (const float4*)(cb + ((size_t)1 * NK + idx_s[1 * BM + row]) * DDIM);
        const float4* c2 = (const float4*)(cb + ((size_t)2 * NK + idx_s[2 * BM + row]) * DDIM);
        const float4* c3 = (const float4*)(cb + ((size_t)3 * NK + idx_s[3 * BM + row]) * DDIM);
#pragma unroll
        for (int k = 0; k < 8; ++k) {
            int p = sub + k * 16;
            float4 q0 = c0[p], q1 = c1[p], q2 = c2[p], q3 = c3[p];
            float4 q;
            q.x = ((q0.x + q1.x) + q2.x) + q3.x;
            q.y = ((q0.y + q1.y) + q2.y) + q3.y;
            q.z = ((q0.z + q1.z) + q2.z) + q3.z;
            q.w = ((q0.w + q1.w) + q2.w) + q3.w;
            float4 zv = zrow[p];
            float4 st;
            st.x = zv.x + (q.x - zv.x);
            st.y = zv.y + (q.y - zv.y);
            st.z = zv.z + (q.z - zv.z);
            st.w = zv.w + (q.w - zv.w);
            rrow[p] = st;
        }
    }
    __syncthreads();

    const int colg = tid & 31;
    const int rowg = tid >> 5;
    const int c0_  = colg * 4;
    const int hr0  = rowg * 2;

    // ---- 4) h1 = relu(st @ w1 + b1) ----
    {
        float acc[2][4] = {{0.f, 0.f, 0.f, 0.f}, {0.f, 0.f, 0.f, 0.f}};
        for (int d = 0; d < DDIM; d += 4) {
            float4 a0 = *(const float4*)&resid[hr0 * DDIM + d];
            float4 a1 = *(const float4*)&resid[(hr0 + 1) * DDIM + d];
            float a0f[4] = {a0.x, a0.y, a0.z, a0.w};
            float a1f[4] = {a1.x, a1.y, a1.z, a1.w};
#pragma unroll
            for (int dd = 0; dd < 4; ++dd) {
                float4 wv2 = *(const float4*)&w1[(size_t)(d + dd) * NH + c0_];
                acc[0][0] = fmaf(a0f[dd], wv2.x, acc[0][0]);
                acc[0][1] = fmaf(a0f[dd], wv2.y, acc[0][1]);
                acc[0][2] = fmaf(a0f[dd], wv2.z, acc[0][2]);
                acc[0][3] = fmaf(a0f[dd], wv2.w, acc[0][3]);
                acc[1][0] = fmaf(a1f[dd], wv2.x, acc[1][0]);
                acc[1][1] = fmaf(a1f[dd], wv2.y, acc[1][1]);
                acc[1][2] = fmaf(a1f[dd], wv2.z, acc[1][2]);
                acc[1][3] = fmaf(a1f[dd], wv2.w, acc[1][3]);
            }
        }
        float4 bv = *(const float4*)&b1[c0_];
        float bf[4] = {bv.x, bv.y, bv.z, bv.w};
#pragma unroll
        for (int r = 0; r < 2; ++r) {
            float4 o;
            o.x = fmaxf(acc[r][0] + bf[0], 0.f);
            o.y = fmaxf(acc[r][1] + bf[1], 0.f);
            o.z = fmaxf(acc[r][2] + bf[2], 0.f);
            o.w = fmaxf(acc[r][3] + bf[3], 0.f);
            *(float4*)&h1[(hr0 + r) * NH + c0_] = o;
        }
    }
    __syncthreads();

    // ---- 5) h2 = relu(h1 @ w2 + b2), stored into resid region ----
    float* h2 = resid;
    {
        float acc[2][4] = {{0.f, 0.f, 0.f, 0.f}, {0.f, 0.f, 0.f, 0.f}};
        for (int d = 0; d < NH; d += 4) {
            float4 a0 = *(const float4*)&h1[hr0 * NH + d];
            float4 a1 = *(const float4*)&h1[(hr0 + 1) * NH + d];
            float a0f[4] = {a0.x, a0.y, a0.z, a0.w};
            float a1f[4] = {a1.x, a1.y, a1.z, a1.w};
#pragma unroll
            for (int dd = 0; dd < 4; ++dd) {
                float4 wv2 = *(const float4*)&w2[(size_t)(d + dd) * NH + c0_];
                acc[0][0] = fmaf(a0f[dd], wv2.x, acc[0][0]);
                acc[0][1] = fmaf(a0f[dd], wv2.y, acc[0][1]);
                acc[0][2] = fmaf(a0f[dd], wv2.z, acc[0][2]);
                acc[0][3] = fmaf(a0f[dd], wv2.w, acc[0][3]);
                acc[1][0] = fmaf(a1f[dd], wv2.x, acc[1][0]);
                acc[1][1] = fmaf(a1f[dd], wv2.y, acc[1][1]);
                acc[1][2] = fmaf(a1f[dd], wv2.z, acc[1][2]);
                acc[1][3] = fmaf(a1f[dd], wv2.w, acc[1][3]);
            }
        }
        float4 bv = *(const float4*)&b2[c0_];
        float bf[4] = {bv.x, bv.y, bv.z, bv.w};
        __syncthreads();
#pragma unroll
        for (int r = 0; r < 2; ++r) {
            float4 o;
            o.x = fmaxf(acc[r][0] + bf[0], 0.f);
            o.y = fmaxf(acc[r][1] + bf[1], 0.f);
            o.z = fmaxf(acc[r][2] + bf[2], 0.f);
            o.w = fmaxf(acc[r][3] + bf[3], 0.f);
            *(float4*)&h2[(hr0 + r) * NH + c0_] = o;
        }
    }
    __syncthreads();

    // ---- 6) out = h2 @ w3 + b3 ----
    if (tid < BM * NA) {
        const int r = tid / NA;
        const int a = tid - r * NA;
        const float* h2r = &h2[r * NH];
        float s = b3[a];
        for (int h = 0; h < NH; ++h)
            s = fmaf(h2r[h], w3[(size_t)h * NA + a], s);
        out[(row0 + r) * NA + a] = s;
    }
}

extern "C" void kernel_launch(void* const* d_in, const int* in_sizes, int n_in,
                              void* d_out, int out_size, void* d_ws, size_t ws_size,
                              hipStream_t stream) {
    const float* z  = (const float*)d_in[0];
    const float* cb = (const float*)d_in[1];
    const float* w1 = (const float*)d_in[2];
    const float* b1 = (const float*)d_in[3];
    const float* w2 = (const float*)d_in[4];
    const float* b2 = (const float*)d_in[5];
    const float* w3 = (const float*)d_in[6];
    const float* b3 = (const float*)d_in[7];
    float* out = (float*)d_out;
    float* halfnorm = (float*)d_ws;   // NG*NK floats = 16 KB

    (void)hipFuncSetAttribute((const void*)rvq_mlp_fused,
                              hipFuncAttributeMaxDynamicSharedMemorySize,
                              LDS_BYTES);

    rvq_norms_np<<<dim3((NG * NK + 255) / 256), dim3(256), 0, stream>>>(cb, halfnorm);
    rvq_mlp_fused<<<dim3(B_ROWS / BM), dim3(NTHREADS), LDS_BYTES, stream>>>(
        z, cb, halfnorm, w1, b1, w2, b2, w3, b3, out);
}

// Round 9
// 4819.032 us; speedup vs baseline: 3.7805x; 1.9401x over previous
//
#include <hip/hip_runtime.h>
#include <math.h>

// Problem dims (fixed by setup_inputs)
#define B_ROWS 65536
#define DDIM   512
#define NG     4
#define NK     1024
#define NH     128
#define NA     7

// Tiling: 8 waves = 4 row-groups (TR=8) x 2 cw-groups (TC=4 consecutive cw
// per lane). B comes straight from the pre-transposed codebook in global
// (L2-resident), coalesced dwordx4 per wave; A is wave-uniform LDS broadcast.
// No LDS staging, no barriers in the k-loop. acc = 2*TR*TC = 64 VGPRs.
#define BM       32
#define NTHREADS 512
#define TR       8
#define TC       4
#define KSPLIT   384            // OpenBLAS sgemm GEMM_Q K-block boundary

// LDS: resid [32][512] fp32 (64KB) + aux region (16KB, aliased: redS/redI/idx
// during VQ, h1 during MLP). Total 80KB -> 2 blocks/CU.
#define OFF_AUX   (BM * DDIM * 4)            // 65536
#define LDS_BYTES (OFF_AUX + BM * NH * 4)    // 81920

// ---------------------------------------------------------------------------
// 0.5 * ||c||^2 emulating numpy fp32 np.sum(C*C, axis=-1):
// pairwise_sum, AVX512 SIMD variant (vstep=16, PW_BLOCKSIZE=128).
// fp contract OFF: each square rounds before add.
// ---------------------------------------------------------------------------
__global__ void rvq_norms_np(const float* __restrict__ cb,
                             float* __restrict__ halfnorm) {
#pragma clang fp contract(off)
    int k = blockIdx.x * blockDim.x + threadIdx.x;
    if (k >= NG * NK) return;
    const float* c = cb + (size_t)k * DDIM;
    float blk[4];
#pragma unroll
    for (int b = 0; b < 4; ++b) {
        const float* p = c + b * 128;
        float s[16];
#pragma unroll
        for (int l = 0; l < 16; ++l) {
            float x0 = p[l],      x1 = p[l + 16], x2 = p[l + 32], x3 = p[l + 48];
            float x4 = p[l + 64], x5 = p[l + 80], x6 = p[l + 96], x7 = p[l + 112];
            float pa = x0 * x0 + x4 * x4;
            float pb = x1 * x1 + x5 * x5;
            float pc = x2 * x2 + x6 * x6;
            float pd = x3 * x3 + x7 * x7;
            s[l] = (pa + pb) + (pc + pd);
        }
        float h[8];
#pragma unroll
        for (int l = 0; l < 8; ++l) h[l] = s[l] + s[l + 8];
        float q[4];
#pragma unroll
        for (int l = 0; l < 4; ++l) q[l] = h[l] + h[l + 4];
        float r0 = q[0] + q[2];
        float r1 = q[1] + q[3];
        blk[b] = r0 + r1;
    }
    float total = (blk[0] + blk[1]) + (blk[2] + blk[3]);
    halfnorm[k] = 0.5f * total;
}

// ---------------------------------------------------------------------------
// Codebook transpose: cbT[g][d][cw] = cb[g][cw][d]. Coalesced both sides via
// a padded 32x32 LDS tile. Bit-exact copy.
// ---------------------------------------------------------------------------
__global__ void rvq_transpose(const float* __restrict__ cb,
                              float* __restrict__ cbT) {
    __shared__ float tile[32][33];
    const int g   = blockIdx.z;
    const int cw0 = blockIdx.x * 32;
    const int d0  = blockIdx.y * 32;
    const int tx  = threadIdx.x, ty = threadIdx.y;   // 32 x 8
    const float* src = cb + ((size_t)g * NK + cw0) * DDIM + d0;
#pragma unroll
    for (int ph = 0; ph < 4; ++ph)
        tile[ty + ph * 8][tx] = src[(size_t)(ty + ph * 8) * DDIM + tx];
    __syncthreads();
    float* dst = cbT + ((size_t)g * DDIM + d0) * NK + cw0;
#pragma unroll
    for (int ph = 0; ph < 4; ++ph)
        dst[(size_t)(ty + ph * 8) * NK + tx] = tile[tx][ty + ph * 8];
}

// One 4-k step of the bit-exact sequential fp32 FMA chain (k = d4..d4+3,
// ascending). A: TR wave-uniform LDS b128 broadcasts. B: bv[dd] preloaded
// from global cbT (coalesced). Per acc[r][j] the chain order is dd ascending
// within the step, steps ascending -> strictly ascending k.
#define STEP(ACC)                                                            \
    _Pragma("unroll")                                                        \
    for (int r = 0; r < TR; ++r) {                                           \
        float4 av = *(const float4*)&resid[(r0 + r) * DDIM + d4];            \
        const float* avf = (const float*)&av;                                \
        _Pragma("unroll")                                                    \
        for (int dd = 0; dd < 4; ++dd) {                                     \
            const float a = avf[dd];                                         \
            const float* bf = (const float*)&bv[dd];                         \
            ACC[r][0] = fmaf(a, bf[0], ACC[r][0]);                           \
            ACC[r][1] = fmaf(a, bf[1], ACC[r][1]);                           \
            ACC[r][2] = fmaf(a, bf[2], ACC[r][2]);                           \
            ACC[r][3] = fmaf(a, bf[3], ACC[r][3]);                           \
        }                                                                    \
    }

// ---------------------------------------------------------------------------
// Fused: residual VQ (4 stages, np-fp32-emulated scoring; B from transposed
// codebook in global, A from LDS, barrier-free k-loop) + reference-order
// quantized sum + straight-through + MLP (512->128->128->7).
// ---------------------------------------------------------------------------
__global__ __launch_bounds__(NTHREADS, 2) void rvq_mlp_fused(
    const float* __restrict__ z, const float* __restrict__ cb,
    const float* __restrict__ cbT, const float* __restrict__ halfnorm,
    const float* __restrict__ w1, const float* __restrict__ b1,
    const float* __restrict__ w2, const float* __restrict__ b2,
    const float* __restrict__ w3, const float* __restrict__ b3,
    float* __restrict__ out) {
    extern __shared__ char smem[];
    float* resid = (float*)smem;                       // [BM][DDIM]
    float* redS  = (float*)(smem + OFF_AUX);           // [2][BM]
    int*   redI  = (int*)(smem + OFF_AUX + 256);       // [2][BM]
    int*   idx_s = (int*)(smem + OFF_AUX + 512);       // [NG][BM]
    float* h1    = (float*)(smem + OFF_AUX);           // [BM][NH], aliases aux
                                                       // (used only after idx dead)

    const int tid = threadIdx.x;
    const size_t row0 = (size_t)blockIdx.x * BM;

    // ---- 1) load z tile into LDS ----
    {
        const float4* src = (const float4*)(z + row0 * DDIM);
        float4* dst = (float4*)resid;
#pragma unroll
        for (int i = 0; i < (BM * DDIM / 4) / NTHREADS; ++i)
            dst[tid + i * NTHREADS] = src[tid + i * NTHREADS];
    }
    __syncthreads();

    const int cg    = tid & 63;       // lane
    const int wv    = tid >> 6;       // wave 0..7
    const int rgrp  = wv & 3;         // row-group (8 rows each)
    const int cwgrp = wv >> 2;        // cw-group (256 cw per pass each)
    const int r0    = rgrp * TR;

    // ---- 2) residual VQ stages ----
    for (int g = 0; g < NG; ++g) {
        const float* Cg = cb + (size_t)g * NK * DDIM;      // row-major (updates)
        const float* Tg = cbT + (size_t)g * DDIM * NK;     // transposed (scores)
        const float* hn = halfnorm + g * NK;

        float sb[TR]; int ib[TR];
#pragma unroll
        for (int r = 0; r < TR; ++r) { sb[r] = -3.4e38f; ib[r] = 0; }

        for (int pass = 0; pass < 2; ++pass) {
            const int cw0 = pass * 512 + cwgrp * 256 + cg * TC;
            const float* bp = Tg + cw0;

            float accA[TR][TC], accB[TR][TC];
#pragma unroll
            for (int r = 0; r < TR; ++r)
#pragma unroll
                for (int j = 0; j < TC; ++j) { accA[r][j] = 0.f; accB[r][j] = 0.f; }

            float4 bv[4], bn[4];
#pragma unroll
            for (int dd = 0; dd < 4; ++dd)
                bv[dd] = *(const float4*)(bp + (size_t)dd * NK);

            // K-block 1: k = 0..383 (prefetch next 4-k group each step)
#pragma unroll 4
            for (int d4 = 0; d4 < KSPLIT; d4 += 4) {
#pragma unroll
                for (int dd = 0; dd < 4; ++dd)
                    bn[dd] = *(const float4*)(bp + (size_t)(d4 + 4 + dd) * NK);
                STEP(accA)
#pragma unroll
                for (int dd = 0; dd < 4; ++dd) bv[dd] = bn[dd];
            }
            // K-block 2: k = 384..511
#pragma unroll 4
            for (int d4 = KSPLIT; d4 < DDIM; d4 += 4) {
                if (d4 < DDIM - 4) {
#pragma unroll
                    for (int dd = 0; dd < 4; ++dd)
                        bn[dd] = *(const float4*)(bp + (size_t)(d4 + 4 + dd) * NK);
                }
                STEP(accB)
#pragma unroll
                for (int dd = 0; dd < 4; ++dd) bv[dd] = bn[dd];
            }

            // score = fl(S1+S2) - hn ; candidates ascending per lane (pass
            // asc, j asc) -> strict > keeps first occurrence
#pragma unroll
            for (int j = 0; j < TC; ++j) {
                const int cod = cw0 + j;
                const float hnv = hn[cod];
#pragma unroll
                for (int r = 0; r < TR; ++r) {
                    float s = (accA[r][j] + accB[r][j]) - hnv;
                    if (s > sb[r]) { sb[r] = s; ib[r] = cod; }
                }
            }
        }

        // ---- butterfly argmax within wave (ties -> lower index) ----
#pragma unroll
        for (int m = 32; m >= 1; m >>= 1) {
#pragma unroll
            for (int r = 0; r < TR; ++r) {
                float os = __shfl_xor(sb[r], m, 64);
                int   oi = __shfl_xor(ib[r], m, 64);
                if (os > sb[r] || (os == sb[r] && oi < ib[r])) {
                    sb[r] = os; ib[r] = oi;
                }
            }
        }
        if (cg == 0) {
#pragma unroll
            for (int r = 0; r < TR; ++r) {
                redS[cwgrp * BM + r0 + r] = sb[r];
                redI[cwgrp * BM + r0 + r] = ib[r];
            }
        }
        __syncthreads();
        // combine the two cw-groups per row (global first-occurrence ties)
        if (tid < BM) {
            float sA = redS[tid], sB = redS[BM + tid];
            int   iA = redI[tid], iB = redI[BM + tid];
            idx_s[g * BM + tid] =
                (sB > sA || (sB == sA && iB < iA)) ? iB : iA;
        }
        __syncthreads();

        // ---- residual -= chosen codeword (exact fp32); skip after last ----
        if (g < NG - 1) {
            const int row = tid >> 4;
            const int sub = tid & 15;
            const float4* crow =
                (const float4*)(Cg + (size_t)idx_s[g * BM + row] * DDIM);
            float4* rrow = (float4*)&resid[row * DDIM];
#pragma unroll
            for (int k = 0; k < 8; ++k) {
                int p = sub + k * 16;
                float4 rv = rrow[p], cv = crow[p];
                rv.x -= cv.x; rv.y -= cv.y; rv.z -= cv.z; rv.w -= cv.w;
                rrow[p] = rv;
            }
            __syncthreads();
        }
    }

    // ---- 3) st = z + (zq - z), zq in reference order (((0+q0)+q1)+q2)+q3 ----
    {
        const int row = tid >> 4;
        const int sub = tid & 15;
        const float4* zrow = (const float4*)(z + (row0 + row) * DDIM);
        float4* rrow = (float4*)&resid[row * DDIM];
        const float4* c0 = (const float4*)(cb + ((size_t)0 * NK + idx_s[0 * BM + row]) * DDIM);
        const float4* c1 = (const float4*)(cb + ((size_t)1 * NK + idx_s[1 * BM + row]) * DDIM);
        const float4* c2 = (const float4*)(cb + ((size_t)2 * NK + idx_s[2 * BM + row]) * DDIM);
        const float4* c3 = (const float4*)(cb + ((size_t)3 * NK + idx_s[3 * BM + row]) * DDIM);
#pragma unroll
        for (int k = 0; k < 8; ++k) {
            int p = sub + k * 16;
            float4 q0 = c0[p], q1 = c1[p], q2 = c2[p], q3 = c3[p];
            float4 q;
            q.x = ((q0.x + q1.x) + q2.x) + q3.x;
            q.y = ((q0.y + q1.y) + q2.y) + q3.y;
            q.z = ((q0.z + q1.z) + q2.z) + q3.z;
            q.w = ((q0.w + q1.w) + q2.w) + q3.w;
            float4 zv = zrow[p];
            float4 st;
            st.x = zv.x + (q.x - zv.x);
            st.y = zv.y + (q.y - zv.y);
            st.z = zv.z + (q.z - zv.z);
            st.w = zv.w + (q.w - zv.w);
            rrow[p] = st;
        }
    }
    __syncthreads();   // idx reads done; aux region may now become h1

    const int colg = tid & 31;
    const int rowg = tid >> 5;
    const int c0_  = colg * 4;
    const int hr0  = rowg * 2;

    // ---- 4) h1 = relu(st @ w1 + b1) ----
    {
        float acc[2][4] = {{0.f, 0.f, 0.f, 0.f}, {0.f, 0.f, 0.f, 0.f}};
        for (int d = 0; d < DDIM; d += 4) {
            float4 a0 = *(const float4*)&resid[hr0 * DDIM + d];
            float4 a1 = *(const float4*)&resid[(hr0 + 1) * DDIM + d];
            float a0f[4] = {a0.x, a0.y, a0.z, a0.w};
            float a1f[4] = {a1.x, a1.y, a1.z, a1.w};
#pragma unroll
            for (int dd = 0; dd < 4; ++dd) {
                float4 wv2 = *(const float4*)&w1[(size_t)(d + dd) * NH + c0_];
                acc[0][0] = fmaf(a0f[dd], wv2.x, acc[0][0]);
                acc[0][1] = fmaf(a0f[dd], wv2.y, acc[0][1]);
                acc[0][2] = fmaf(a0f[dd], wv2.z, acc[0][2]);
                acc[0][3] = fmaf(a0f[dd], wv2.w, acc[0][3]);
                acc[1][0] = fmaf(a1f[dd], wv2.x, acc[1][0]);
                acc[1][1] = fmaf(a1f[dd], wv2.y, acc[1][1]);
                acc[1][2] = fmaf(a1f[dd], wv2.z, acc[1][2]);
                acc[1][3] = fmaf(a1f[dd], wv2.w, acc[1][3]);
            }
        }
        float4 bv = *(const float4*)&b1[c0_];
        float bf[4] = {bv.x, bv.y, bv.z, bv.w};
#pragma unroll
        for (int r = 0; r < 2; ++r) {
            float4 o;
            o.x = fmaxf(acc[r][0] + bf[0], 0.f);
            o.y = fmaxf(acc[r][1] + bf[1], 0.f);
            o.z = fmaxf(acc[r][2] + bf[2], 0.f);
            o.w = fmaxf(acc[r][3] + bf[3], 0.f);
            *(float4*)&h1[(hr0 + r) * NH + c0_] = o;
        }
    }
    __syncthreads();

    // ---- 5) h2 = relu(h1 @ w2 + b2), stored into resid region ----
    float* h2 = resid;
    {
        float acc[2][4] = {{0.f, 0.f, 0.f, 0.f}, {0.f, 0.f, 0.f, 0.f}};
        for (int d = 0; d < NH; d += 4) {
            float4 a0 = *(const float4*)&h1[hr0 * NH + d];
            float4 a1 = *(const float4*)&h1[(hr0 + 1) * NH + d];
            float a0f[4] = {a0.x, a0.y, a0.z, a0.w};
            float a1f[4] = {a1.x, a1.y, a1.z, a1.w};
#pragma unroll
            for (int dd = 0; dd < 4; ++dd) {
                float4 wv2 = *(const float4*)&w2[(size_t)(d + dd) * NH + c0_];
                acc[0][0] = fmaf(a0f[dd], wv2.x, acc[0][0]);
                acc[0][1] = fmaf(a0f[dd], wv2.y, acc[0][1]);
                acc[0][2] = fmaf(a0f[dd], wv2.z, acc[0][2]);
                acc[0][3] = fmaf(a0f[dd], wv2.w, acc[0][3]);
                acc[1][0] = fmaf(a1f[dd], wv2.x, acc[1][0]);
                acc[1][1] = fmaf(a1f[dd], wv2.y, acc[1][1]);
                acc[1][2] = fmaf(a1f[dd], wv2.z, acc[1][2]);
                acc[1][3] = fmaf(a1f[dd], wv2.w, acc[1][3]);
            }
        }
        float4 bv = *(const float4*)&b2[c0_];
        float bf[4] = {bv.x, bv.y, bv.z, bv.w};
        __syncthreads();
#pragma unroll
        for (int r = 0; r < 2; ++r) {
            float4 o;
            o.x = fmaxf(acc[r][0] + bf[0], 0.f);
            o.y = fmaxf(acc[r][1] + bf[1], 0.f);
            o.z = fmaxf(acc[r][2] + bf[2], 0.f);
            o.w = fmaxf(acc[r][3] + bf[3], 0.f);
            *(float4*)&h2[(hr0 + r) * NH + c0_] = o;
        }
    }
    __syncthreads();

    // ---- 6) out = h2 @ w3 + b3 ----
    if (tid < BM * NA) {
        const int r = tid / NA;
        const int a = tid - r * NA;
        const float* h2r = &h2[r * NH];
        float s = b3[a];
        for (int h = 0; h < NH; ++h)
            s = fmaf(h2r[h], w3[(size_t)h * NA + a], s);
        out[(row0 + r) * NA + a] = s;
    }
}

extern "C" void kernel_launch(void* const* d_in, const int* in_sizes, int n_in,
                              void* d_out, int out_size, void* d_ws, size_t ws_size,
                              hipStream_t stream) {
    const float* z  = (const float*)d_in[0];
    const float* cb = (const float*)d_in[1];
    const float* w1 = (const float*)d_in[2];
    const float* b1 = (const float*)d_in[3];
    const float* w2 = (const float*)d_in[4];
    const float* b2 = (const float*)d_in[5];
    const float* w3 = (const float*)d_in[6];
    const float* b3 = (const float*)d_in[7];
    float* out = (float*)d_out;

    float* halfnorm = (float*)d_ws;             // NG*NK floats = 16 KB
    float* cbT      = (float*)d_ws + NG * NK;   // NG*DDIM*NK floats = 8 MB

    (void)hipFuncSetAttribute((const void*)rvq_mlp_fused,
                              hipFuncAttributeMaxDynamicSharedMemorySize,
                              LDS_BYTES);

    rvq_norms_np<<<dim3((NG * NK + 255) / 256), dim3(256), 0, stream>>>(cb, halfnorm);
    rvq_transpose<<<dim3(NK / 32, DDIM / 32, NG), dim3(32, 8), 0, stream>>>(cb, cbT);
    rvq_mlp_fused<<<dim3(B_ROWS / BM), dim3(NTHREADS), LDS_BYTES, stream>>>(
        z, cb, cbT, halfnorm, w1, b1, w2, b2, w3, b3, out);
}

// Round 10
// 3895.075 us; speedup vs baseline: 4.6773x; 1.2372x over previous
//
#include <hip/hip_runtime.h>
#include <math.h>

// Problem dims (fixed by setup_inputs)
#define B_ROWS 65536
#define DDIM   512
#define NG     4
#define NK     1024
#define NH     128
#define NA     7

// Tiling: 8 waves = 4 row-groups (TR=8) x 2 cw-groups. Lane covers TC=8
// codewords as TWO 4-consecutive groups (cw0, cw0+256): every B
// global_load_dwordx4 spans 1KB contiguous per wave. ONE pass over all
// 1024 codewords. acc = accA+accB = 128 VGPRs; launch_bounds(512,1)
// lifts the per-wave VGPR cap to 256 (r6-r9 were silently capped at 128
// by min-2-waves/EU and spilled).
#define BM       32
#define NTHREADS 512
#define TR       8
#define TC       8
#define KSPLIT   384            // OpenBLAS sgemm GEMM_Q K-block boundary

// LDS: resid [32][512] fp32 (64KB) + aux region (16KB, aliased: redS/redI/idx
// during VQ, h1 during MLP).
#define OFF_AUX   (BM * DDIM * 4)            // 65536
#define LDS_BYTES (OFF_AUX + BM * NH * 4)    // 81920

// ---------------------------------------------------------------------------
// 0.5 * ||c||^2 emulating numpy fp32 np.sum(C*C, axis=-1):
// pairwise_sum, AVX512 SIMD variant (vstep=16, PW_BLOCKSIZE=128).
// fp contract OFF: each square rounds before add.
// ---------------------------------------------------------------------------
__global__ void rvq_norms_np(const float* __restrict__ cb,
                             float* __restrict__ halfnorm) {
#pragma clang fp contract(off)
    int k = blockIdx.x * blockDim.x + threadIdx.x;
    if (k >= NG * NK) return;
    const float* c = cb + (size_t)k * DDIM;
    float blk[4];
#pragma unroll
    for (int b = 0; b < 4; ++b) {
        const float* p = c + b * 128;
        float s[16];
#pragma unroll
        for (int l = 0; l < 16; ++l) {
            float x0 = p[l],      x1 = p[l + 16], x2 = p[l + 32], x3 = p[l + 48];
            float x4 = p[l + 64], x5 = p[l + 80], x6 = p[l + 96], x7 = p[l + 112];
            float pa = x0 * x0 + x4 * x4;
            float pb = x1 * x1 + x5 * x5;
            float pc = x2 * x2 + x6 * x6;
            float pd = x3 * x3 + x7 * x7;
            s[l] = (pa + pb) + (pc + pd);
        }
        float h[8];
#pragma unroll
        for (int l = 0; l < 8; ++l) h[l] = s[l] + s[l + 8];
        float q[4];
#pragma unroll
        for (int l = 0; l < 4; ++l) q[l] = h[l] + h[l + 4];
        float r0 = q[0] + q[2];
        float r1 = q[1] + q[3];
        blk[b] = r0 + r1;
    }
    float total = (blk[0] + blk[1]) + (blk[2] + blk[3]);
    halfnorm[k] = 0.5f * total;
}

// ---------------------------------------------------------------------------
// Codebook transpose: cbT[g][d][cw] = cb[g][cw][d]. Coalesced both sides via
// a padded 32x32 LDS tile. Bit-exact copy.
// ---------------------------------------------------------------------------
__global__ void rvq_transpose(const float* __restrict__ cb,
                              float* __restrict__ cbT) {
    __shared__ float tile[32][33];
    const int g   = blockIdx.z;
    const int cw0 = blockIdx.x * 32;
    const int d0  = blockIdx.y * 32;
    const int tx  = threadIdx.x, ty = threadIdx.y;   // 32 x 8
    const float* src = cb + ((size_t)g * NK + cw0) * DDIM + d0;
#pragma unroll
    for (int ph = 0; ph < 4; ++ph)
        tile[ty + ph * 8][tx] = src[(size_t)(ty + ph * 8) * DDIM + tx];
    __syncthreads();
    float* dst = cbT + ((size_t)g * DDIM + d0) * NK + cw0;
#pragma unroll
    for (int ph = 0; ph < 4; ++ph)
        dst[(size_t)(ty + ph * 8) * NK + tx] = tile[tx][ty + ph * 8];
}

// One 4-k step of the bit-exact sequential fp32 FMA chain (k = d4..d4+3,
// ascending). A: TR wave-uniform LDS b128 broadcasts (amortized over TC=8).
// B: bv[0..3] = group1 (cw0+{0..3}), bv[4..7] = group2 (cw0+256+{0..3}),
// preloaded from global cbT. Per acc[r][j]: dd ascending within step,
// steps ascending -> strictly ascending k.
#define STEP(ACC)                                                            \
    _Pragma("unroll")                                                        \
    for (int r = 0; r < TR; ++r) {                                           \
        float4 av = *(const float4*)&resid[(r0 + r) * DDIM + d4];            \
        const float* avf = (const float*)&av;                                \
        _Pragma("unroll")                                                    \
        for (int dd = 0; dd < 4; ++dd) {                                     \
            const float a = avf[dd];                                         \
            const float* b1f = (const float*)&bv[dd];                        \
            const float* b2f = (const float*)&bv[4 + dd];                    \
            ACC[r][0] = fmaf(a, b1f[0], ACC[r][0]);                          \
            ACC[r][1] = fmaf(a, b1f[1], ACC[r][1]);                          \
            ACC[r][2] = fmaf(a, b1f[2], ACC[r][2]);                          \
            ACC[r][3] = fmaf(a, b1f[3], ACC[r][3]);                          \
            ACC[r][4] = fmaf(a, b2f[0], ACC[r][4]);                          \
            ACC[r][5] = fmaf(a, b2f[1], ACC[r][5]);                          \
            ACC[r][6] = fmaf(a, b2f[2], ACC[r][6]);                          \
            ACC[r][7] = fmaf(a, b2f[3], ACC[r][7]);                          \
        }                                                                    \
    }

#define LOADB(DST, ROW)                                                      \
    _Pragma("unroll")                                                        \
    for (int dd = 0; dd < 4; ++dd) {                                         \
        DST[dd]     = *(const float4*)(bp + (size_t)((ROW) + dd) * NK);      \
        DST[4 + dd] = *(const float4*)(bp + (size_t)((ROW) + dd) * NK + 256);\
    }

// ---------------------------------------------------------------------------
// Fused: residual VQ (4 stages, np-fp32-emulated scoring; B from transposed
// codebook in global/L2, A from LDS, barrier-free k-loop) + reference-order
// quantized sum + straight-through + MLP (512->128->128->7).
// ---------------------------------------------------------------------------
__global__ __launch_bounds__(NTHREADS, 1) void rvq_mlp_fused(
    const float* __restrict__ z, const float* __restrict__ cb,
    const float* __restrict__ cbT, const float* __restrict__ halfnorm,
    const float* __restrict__ w1, const float* __restrict__ b1,
    const float* __restrict__ w2, const float* __restrict__ b2,
    const float* __restrict__ w3, const float* __restrict__ b3,
    float* __restrict__ out) {
    extern __shared__ char smem[];
    float* resid = (float*)smem;                       // [BM][DDIM]
    float* redS  = (float*)(smem + OFF_AUX);           // [2][BM]
    int*   redI  = (int*)(smem + OFF_AUX + 256);       // [2][BM]
    int*   idx_s = (int*)(smem + OFF_AUX + 512);       // [NG][BM]
    float* h1    = (float*)(smem + OFF_AUX);           // [BM][NH], aliases aux
                                                       // (used only after idx dead)

    const int tid = threadIdx.x;
    const size_t row0 = (size_t)blockIdx.x * BM;

    // ---- 1) load z tile into LDS ----
    {
        const float4* src = (const float4*)(z + row0 * DDIM);
        float4* dst = (float4*)resid;
#pragma unroll
        for (int i = 0; i < (BM * DDIM / 4) / NTHREADS; ++i)
            dst[tid + i * NTHREADS] = src[tid + i * NTHREADS];
    }
    __syncthreads();

    const int cg    = tid & 63;       // lane
    const int wv    = tid >> 6;       // wave 0..7
    const int rgrp  = wv & 3;         // row-group (8 rows each)
    const int cwgrp = wv >> 2;        // cw-group (512 cw each)
    const int r0    = rgrp * TR;
    const int cw0   = cwgrp * 512 + cg * 4;   // lane cols: cw0+{0..3}, +256+{0..3}

    // ---- 2) residual VQ stages ----
    for (int g = 0; g < NG; ++g) {
        const float* Cg = cb + (size_t)g * NK * DDIM;      // row-major (updates)
        const float* Tg = cbT + (size_t)g * DDIM * NK;     // transposed (scores)
        const float* hn = halfnorm + g * NK;
        const float* bp = Tg + cw0;

        float sb[TR]; int ib[TR];
#pragma unroll
        for (int r = 0; r < TR; ++r) { sb[r] = -3.4e38f; ib[r] = 0; }

        float accA[TR][TC], accB[TR][TC];
#pragma unroll
        for (int r = 0; r < TR; ++r)
#pragma unroll
            for (int j = 0; j < TC; ++j) { accA[r][j] = 0.f; accB[r][j] = 0.f; }

        float4 bv[8], bn[8];
        LOADB(bv, 0)

        // K-block 1: k = 0..383 (prefetch next 4-k group each step)
#pragma unroll 2
        for (int d4 = 0; d4 < KSPLIT; d4 += 4) {
            LOADB(bn, d4 + 4)
            STEP(accA)
#pragma unroll
            for (int q = 0; q < 8; ++q) bv[q] = bn[q];
        }
        // K-block 2: k = 384..511
#pragma unroll 2
        for (int d4 = KSPLIT; d4 < DDIM; d4 += 4) {
            if (d4 < DDIM - 4) { LOADB(bn, d4 + 4) }
            STEP(accB)
#pragma unroll
            for (int q = 0; q < 8; ++q) bv[q] = bn[q];
        }

        // score = fl(S1+S2) - hn ; candidates ascending per lane
        // (j 0..3 -> cw0+j ; j 4..7 -> cw0+256+(j-4)) -> strict > keeps
        // first occurrence
#pragma unroll
        for (int j = 0; j < TC; ++j) {
            const int cod = cw0 + (j < 4 ? j : 256 + (j - 4));
            const float hnv = hn[cod];
#pragma unroll
            for (int r = 0; r < TR; ++r) {
                float s = (accA[r][j] + accB[r][j]) - hnv;
                if (s > sb[r]) { sb[r] = s; ib[r] = cod; }
            }
        }

        // ---- butterfly argmax within wave (ties -> lower index) ----
#pragma unroll
        for (int m = 32; m >= 1; m >>= 1) {
#pragma unroll
            for (int r = 0; r < TR; ++r) {
                float os = __shfl_xor(sb[r], m, 64);
                int   oi = __shfl_xor(ib[r], m, 64);
                if (os > sb[r] || (os == sb[r] && oi < ib[r])) {
                    sb[r] = os; ib[r] = oi;
                }
            }
        }
        if (cg == 0) {
#pragma unroll
            for (int r = 0; r < TR; ++r) {
                redS[cwgrp * BM + r0 + r] = sb[r];
                redI[cwgrp * BM + r0 + r] = ib[r];
            }
        }
        __syncthreads();
        // combine the two cw-groups per row (global first-occurrence ties)
        if (tid < BM) {
            float sA = redS[tid], sB = redS[BM + tid];
            int   iA = redI[tid], iB = redI[BM + tid];
            idx_s[g * BM + tid] =
                (sB > sA || (sB == sA && iB < iA)) ? iB : iA;
        }
        __syncthreads();

        // ---- residual -= chosen codeword (exact fp32); skip after last ----
        if (g < NG - 1) {
            const int row = tid >> 4;
            const int sub = tid & 15;
            const float4* crow =
                (const float4*)(Cg + (size_t)idx_s[g * BM + row] * DDIM);
            float4* rrow = (float4*)&resid[row * DDIM];
#pragma unroll
            for (int k = 0; k < 8; ++k) {
                int p = sub + k * 16;
                float4 rv = rrow[p], cv = crow[p];
                rv.x -= cv.x; rv.y -= cv.y; rv.z -= cv.z; rv.w -= cv.w;
                rrow[p] = rv;
            }
            __syncthreads();
        }
    }

    // ---- 3) st = z + (zq - z), zq in reference order (((0+q0)+q1)+q2)+q3 ----
    {
        const int row = tid >> 4;
        const int sub = tid & 15;
        const float4* zrow = (const float4*)(z + (row0 + row) * DDIM);
        float4* rrow = (float4*)&resid[row * DDIM];
        const float4* c0 = (const float4*)(cb + ((size_t)0 * NK + idx_s[0 * BM + row]) * DDIM);
        const float4* c1 = (const float4*)(cb + ((size_t)1 * NK + idx_s[1 * BM + row]) * DDIM);
        const float4* c2 = (const float4*)(cb + ((size_t)2 * NK + idx_s[2 * BM + row]) * DDIM);
        const float4* c3 = (const float4*)(cb + ((size_t)3 * NK + idx_s[3 * BM + row]) * DDIM);
#pragma unroll
        for (int k = 0; k < 8; ++k) {
            int p = sub + k * 16;
            float4 q0 = c0[p], q1 = c1[p], q2 = c2[p], q3 = c3[p];
            float4 q;
            q.x = ((q0.x + q1.x) + q2.x) + q3.x;
            q.y = ((q0.y + q1.y) + q2.y) + q3.y;
            q.z = ((q0.z + q1.z) + q2.z) + q3.z;
            q.w = ((q0.w + q1.w) + q2.w) + q3.w;
            float4 zv = zrow[p];
            float4 st;
            st.x = zv.x + (q.x - zv.x);
            st.y = zv.y + (q.y - zv.y);
            st.z = zv.z + (q.z - zv.z);
            st.w = zv.w + (q.w - zv.w);
            rrow[p] = st;
        }
    }
    __syncthreads();   // idx reads done; aux region may now become h1

    const int colg = tid & 31;
    const int rowg = tid >> 5;
    const int c0_  = colg * 4;
    const int hr0  = rowg * 2;

    // ---- 4) h1 = relu(st @ w1 + b1) ----
    {
        float acc[2][4] = {{0.f, 0.f, 0.f, 0.f}, {0.f, 0.f, 0.f, 0.f}};
        for (int d = 0; d < DDIM; d += 4) {
            float4 a0 = *(const float4*)&resid[hr0 * DDIM + d];
            float4 a1 = *(const float4*)&resid[(hr0 + 1) * DDIM + d];
            float a0f[4] = {a0.x, a0.y, a0.z, a0.w};
            float a1f[4] = {a1.x, a1.y, a1.z, a1.w};
#pragma unroll
            for (int dd = 0; dd < 4; ++dd) {
                float4 wv2 = *(const float4*)&w1[(size_t)(d + dd) * NH + c0_];
                acc[0][0] = fmaf(a0f[dd], wv2.x, acc[0][0]);
                acc[0][1] = fmaf(a0f[dd], wv2.y, acc[0][1]);
                acc[0][2] = fmaf(a0f[dd], wv2.z, acc[0][2]);
                acc[0][3] = fmaf(a0f[dd], wv2.w, acc[0][3]);
                acc[1][0] = fmaf(a1f[dd], wv2.x, acc[1][0]);
                acc[1][1] = fmaf(a1f[dd], wv2.y, acc[1][1]);
                acc[1][2] = fmaf(a1f[dd], wv2.z, acc[1][2]);
                acc[1][3] = fmaf(a1f[dd], wv2.w, acc[1][3]);
            }
        }
        float4 bv = *(const float4*)&b1[c0_];
        float bf[4] = {bv.x, bv.y, bv.z, bv.w};
#pragma unroll
        for (int r = 0; r < 2; ++r) {
            float4 o;
            o.x = fmaxf(acc[r][0] + bf[0], 0.f);
            o.y = fmaxf(acc[r][1] + bf[1], 0.f);
            o.z = fmaxf(acc[r][2] + bf[2], 0.f);
            o.w = fmaxf(acc[r][3] + bf[3], 0.f);
            *(float4*)&h1[(hr0 + r) * NH + c0_] = o;
        }
    }
    __syncthreads();

    // ---- 5) h2 = relu(h1 @ w2 + b2), stored into resid region ----
    float* h2 = resid;
    {
        float acc[2][4] = {{0.f, 0.f, 0.f, 0.f}, {0.f, 0.f, 0.f, 0.f}};
        for (int d = 0; d < NH; d += 4) {
            float4 a0 = *(const float4*)&h1[hr0 * NH + d];
            float4 a1 = *(const float4*)&h1[(hr0 + 1) * NH + d];
            float a0f[4] = {a0.x, a0.y, a0.z, a0.w};
            float a1f[4] = {a1.x, a1.y, a1.z, a1.w};
#pragma unroll
            for (int dd = 0; dd < 4; ++dd) {
                float4 wv2 = *(const float4*)&w2[(size_t)(d + dd) * NH + c0_];
                acc[0][0] = fmaf(a0f[dd], wv2.x, acc[0][0]);
                acc[0][1] = fmaf(a0f[dd], wv2.y, acc[0][1]);
                acc[0][2] = fmaf(a0f[dd], wv2.z, acc[0][2]);
                acc[0][3] = fmaf(a0f[dd], wv2.w, acc[0][3]);
                acc[1][0] = fmaf(a1f[dd], wv2.x, acc[1][0]);
                acc[1][1] = fmaf(a1f[dd], wv2.y, acc[1][1]);
                acc[1][2] = fmaf(a1f[dd], wv2.z, acc[1][2]);
                acc[1][3] = fmaf(a1f[dd], wv2.w, acc[1][3]);
            }
        }
        float4 bv = *(const float4*)&b2[c0_];
        float bf[4] = {bv.x, bv.y, bv.z, bv.w};
        __syncthreads();
#pragma unroll
        for (int r = 0; r < 2; ++r) {
            float4 o;
            o.x = fmaxf(acc[r][0] + bf[0], 0.f);
            o.y = fmaxf(acc[r][1] + bf[1], 0.f);
            o.z = fmaxf(acc[r][2] + bf[2], 0.f);
            o.w = fmaxf(acc[r][3] + bf[3], 0.f);
            *(float4*)&h2[(hr0 + r) * NH + c0_] = o;
        }
    }
    __syncthreads();

    // ---- 6) out = h2 @ w3 + b3 ----
    if (tid < BM * NA) {
        const int r = tid / NA;
        const int a = tid - r * NA;
        const float* h2r = &h2[r * NH];
        float s = b3[a];
        for (int h = 0; h < NH; ++h)
            s = fmaf(h2r[h], w3[(size_t)h * NA + a], s);
        out[(row0 + r) * NA + a] = s;
    }
}

extern "C" void kernel_launch(void* const* d_in, const int* in_sizes, int n_in,
                              void* d_out, int out_size, void* d_ws, size_t ws_size,
                              hipStream_t stream) {
    const float* z  = (const float*)d_in[0];
    const float* cb = (const float*)d_in[1];
    const float* w1 = (const float*)d_in[2];
    const float* b1 = (const float*)d_in[3];
    const float* w2 = (const float*)d_in[4];
    const float* b2 = (const float*)d_in[5];
    const float* w3 = (const float*)d_in[6];
    const float* b3 = (const float*)d_in[7];
    float* out = (float*)d_out;

    float* halfnorm = (float*)d_ws;             // NG*NK floats = 16 KB
    float* cbT      = (float*)d_ws + NG * NK;   // NG*DDIM*NK floats = 8 MB

    (void)hipFuncSetAttribute((const void*)rvq_mlp_fused,
                              hipFuncAttributeMaxDynamicSharedMemorySize,
                              LDS_BYTES);

    rvq_norms_np<<<dim3((NG * NK + 255) / 256), dim3(256), 0, stream>>>(cb, halfnorm);
    rvq_transpose<<<dim3(NK / 32, DDIM / 32, NG), dim3(32, 8), 0, stream>>>(cb, cbT);
    rvq_mlp_fused<<<dim3(B_ROWS / BM), dim3(NTHREADS), LDS_BYTES, stream>>>(
        z, cb, cbT, halfnorm, w1, b1, w2, b2, w3, b3, out);
}